// Round 2
// baseline (247.897 us; speedup 1.0000x reference)
//
#include <hip/hip_runtime.h>
#include <math.h>

#define MEM  2048
#define NT   256
#define NBLK (MEM / 2)   // 1024 blocks, 2 rows per block (4 blocks/CU co-resident)

struct Params {
    const float *lc, *rc, *lh, *rh, *S, *w;
    const float *Wh_w, *Wh_b, *Us_w, *Us_b, *ma_w, *ma_b;
    const float *ilh_w, *ilh_b, *irh_w, *irh_b;
    const float *lflh_w, *lflh_b, *lfrh_w, *lfrh_b;
    const float *rflh_w, *rflh_b, *rfrh_w, *rfrh_b;
    const float *ulh_w, *ulh_b, *urh_w, *urh_b;
    float *pl, *pr, *wml, *wmr, *out;
};

__device__ __forceinline__ float dot4(float4 a, float4 b) {
    return a.x * b.x + a.y * b.y + a.z * b.z + a.w * b.w;
}

__device__ __forceinline__ float wave_reduce(float v) {
#pragma unroll
    for (int off = 32; off > 0; off >>= 1)
        v += __shfl_down(v, off, 64);
    return v;
}

// fast tanh/sigmoid via v_exp; |err| ~1e-6 vs libm, tolerance is 3.9e-3.
__device__ __forceinline__ float tanh_fast(float x) {
    x = fminf(15.0f, fmaxf(-15.0f, x));
    const float e = __expf(2.0f * x);
    return (e - 1.0f) / (e + 1.0f);
}
__device__ __forceinline__ float sigmoid_fast(float x) {
    return 1.0f / (1.0f + __expf(-x));
}

// ---- k1: rows r0, r0+1 (r0 = 2*blockIdx):
//   pl[j] = ma_w[j]·lh ; pr[j] = ma_w[j]·rh       (alpha hoisted)
//   m_l = tanh(Wh_w[j]·lh + Wh_b[j] + Us_w[j]·S + Us_b[j]) ; m_r likewise
//   wml[j] = w[j]*m_l ; wmr[j] = w[j]*m_r
__global__ __launch_bounds__(NT, 4) void k1(Params p)
{
    __shared__ float s_red[4][10];

    const int t  = threadIdx.x;
    const int wv = t >> 6, ln = t & 63;
    const int r0 = (int)blockIdx.x * 2;
    const int r1 = r0 + 1;

    // block-uniform per-row scalars -> SGPR loads, hide under the matvec
    const float whb0 = p.Wh_b[r0], whb1 = p.Wh_b[r1];
    const float usb0 = p.Us_b[r0], usb1 = p.Us_b[r1];
    const float w0s  = p.w[r0],    w1s  = p.w[r1];

    const float4* l4 = (const float4*)p.lh;
    const float4* r4 = (const float4*)p.rh;
    const float4* s4 = (const float4*)p.S;
    const float4 xl[2] = { l4[t], l4[t + NT] };
    const float4 xr[2] = { r4[t], r4[t + NT] };
    const float4 xs[2] = { s4[t], s4[t + NT] };

    const float4* wh0 = (const float4*)(p.Wh_w + (size_t)r0 * MEM);
    const float4* wh1 = (const float4*)(p.Wh_w + (size_t)r1 * MEM);
    const float4* us0 = (const float4*)(p.Us_w + (size_t)r0 * MEM);
    const float4* us1 = (const float4*)(p.Us_w + (size_t)r1 * MEM);
    const float4* ma0 = (const float4*)(p.ma_w + (size_t)r0 * MEM);
    const float4* ma1 = (const float4*)(p.ma_w + (size_t)r1 * MEM);

    float awl0 = 0.f, awr0 = 0.f, aus0 = 0.f, aml0 = 0.f, amr0 = 0.f;
    float awl1 = 0.f, awr1 = 0.f, aus1 = 0.f, aml1 = 0.f, amr1 = 0.f;
#pragma unroll
    for (int h = 0; h < 2; ++h) {
        const int i = t + h * NT;
        const float4 a0 = wh0[i];
        const float4 a1 = wh1[i];
        const float4 u0 = us0[i];
        const float4 u1 = us1[i];
        const float4 m0 = ma0[i];
        const float4 m1 = ma1[i];
        awl0 += dot4(a0, xl[h]);  awl1 += dot4(a1, xl[h]);
        awr0 += dot4(a0, xr[h]);  awr1 += dot4(a1, xr[h]);
        aus0 += dot4(u0, xs[h]);  aus1 += dot4(u1, xs[h]);
        aml0 += dot4(m0, xl[h]);  aml1 += dot4(m1, xl[h]);
        amr0 += dot4(m0, xr[h]);  amr1 += dot4(m1, xr[h]);
    }
    awl0 = wave_reduce(awl0);  awl1 = wave_reduce(awl1);
    awr0 = wave_reduce(awr0);  awr1 = wave_reduce(awr1);
    aus0 = wave_reduce(aus0);  aus1 = wave_reduce(aus1);
    aml0 = wave_reduce(aml0);  aml1 = wave_reduce(aml1);
    amr0 = wave_reduce(amr0);  amr1 = wave_reduce(amr1);

    if (ln == 0) {
        s_red[wv][0] = awl0; s_red[wv][1] = awr0; s_red[wv][2] = aus0;
        s_red[wv][3] = aml0; s_red[wv][4] = amr0;
        s_red[wv][5] = awl1; s_red[wv][6] = awr1; s_red[wv][7] = aus1;
        s_red[wv][8] = aml1; s_red[wv][9] = amr1;
    }
    __syncthreads();
    if (t == 0) {
        const float whbv[2] = { whb0, whb1 };
        const float usbv[2] = { usb0, usb1 };
        const float wsv[2]  = { w0s, w1s };
#pragma unroll
        for (int rr = 0; rr < 2; ++rr) {
            float v0 = 0.f, v1 = 0.f, v2 = 0.f, v3 = 0.f, v4 = 0.f;
#pragma unroll
            for (int k = 0; k < 4; ++k) {
                v0 += s_red[k][rr * 5 + 0];
                v1 += s_red[k][rr * 5 + 1];
                v2 += s_red[k][rr * 5 + 2];
                v3 += s_red[k][rr * 5 + 3];
                v4 += s_red[k][rr * 5 + 4];
            }
            const float usx = v2 + usbv[rr];
            const float ml = tanh_fast(v0 + whbv[rr] + usx);
            const float mr = tanh_fast(v1 + whbv[rr] + usx);
            const int row = r0 + rr;
            p.pl[row]  = v3;
            p.pr[row]  = v4;
            p.wml[row] = wsv[rr] * ml;
            p.wmr[row] = wsv[rr] * mr;
        }
    }
}

// ---- k2: alpha reduce -> la/ra in REGISTERS (each thread consumes exactly
// the elements it computes) -> 16-stream merged matvec for 2 rows.
__global__ __launch_bounds__(NT, 4) void k2(Params p)
{
    __shared__ float s_red[4][8];
    __shared__ float s_al[2];

    const int t  = threadIdx.x;
    const int wv = t >> 6, ln = t & 63;
    const int r0 = (int)blockIdx.x * 2;
    const int r1 = r0 + 1;

    // block-uniform per-row scalars (SGPR), issued before the heavy loads
    const float bI0  = p.ilh_b[r0]  + p.irh_b[r0];
    const float bI1  = p.ilh_b[r1]  + p.irh_b[r1];
    const float bLF0 = p.lflh_b[r0] + p.lfrh_b[r0];
    const float bLF1 = p.lflh_b[r1] + p.lfrh_b[r1];
    const float bRF0 = p.rflh_b[r0] + p.rfrh_b[r0];
    const float bRF1 = p.rflh_b[r1] + p.rfrh_b[r1];
    const float bU0  = p.ulh_b[r0]  + p.urh_b[r0];
    const float bU1  = p.ulh_b[r1]  + p.urh_b[r1];
    const float lc0  = p.lc[r0], lc1 = p.lc[r1];
    const float rc0  = p.rc[r0], rc1 = p.rc[r1];

    // phase 1: alpha (block-redundant reduce of wml/wmr, 16 KB L2-broadcast)
    {
        const float4* wl4 = (const float4*)p.wml;
        const float4* wr4 = (const float4*)p.wmr;
        const float4 a0 = wl4[t], a1 = wl4[t + NT];
        const float4 b0 = wr4[t], b1 = wr4[t + NT];
        float el = a0.x + a0.y + a0.z + a0.w + a1.x + a1.y + a1.z + a1.w;
        float er = b0.x + b0.y + b0.z + b0.w + b1.x + b1.y + b1.z + b1.w;
        el = wave_reduce(el);
        er = wave_reduce(er);
        if (ln == 0) { s_red[wv][0] = el; s_red[wv][1] = er; }
    }
    __syncthreads();
    if (t == 0) {
        const float el = s_red[0][0] + s_red[1][0] + s_red[2][0] + s_red[3][0];
        const float er = s_red[0][1] + s_red[1][1] + s_red[2][1] + s_red[3][1];
        const float d  = el + er;
        s_al[0] = el / d;
        s_al[1] = er / d;
    }
    __syncthreads();
    const float al = s_al[0];
    const float ar = s_al[1];

    // phase 2: la/ra in registers — thread consumes exactly what it computes
    float4 xa[2], xb[2];
    {
        const float4* p4 = (const float4*)p.pl;
        const float4* q4 = (const float4*)p.pr;
        const float4* b4 = (const float4*)p.ma_b;
#pragma unroll
        for (int h = 0; h < 2; ++h) {
            const int i = t + h * NT;
            const float4 pp = p4[i];
            const float4 qq = q4[i];
            const float4 bb = b4[i];
            xa[h].x = tanh_fast(al * pp.x + bb.x); xb[h].x = tanh_fast(ar * qq.x + bb.x);
            xa[h].y = tanh_fast(al * pp.y + bb.y); xb[h].y = tanh_fast(ar * qq.y + bb.y);
            xa[h].z = tanh_fast(al * pp.z + bb.z); xb[h].z = tanh_fast(ar * qq.z + bb.z);
            xa[h].w = tanh_fast(al * pp.w + bb.w); xb[h].w = tanh_fast(ar * qq.w + bb.w);
        }
    }

    // phase 3: merged 16-stream matvec (8 matrices x 2 rows), SGPR bases
    const size_t o0 = (size_t)r0 * MEM;
    const size_t o1 = (size_t)r1 * MEM;
    const float4* il4_0  = (const float4*)(p.ilh_w  + o0);
    const float4* il4_1  = (const float4*)(p.ilh_w  + o1);
    const float4* ir4_0  = (const float4*)(p.irh_w  + o0);
    const float4* ir4_1  = (const float4*)(p.irh_w  + o1);
    const float4* lfl4_0 = (const float4*)(p.lflh_w + o0);
    const float4* lfl4_1 = (const float4*)(p.lflh_w + o1);
    const float4* lfr4_0 = (const float4*)(p.lfrh_w + o0);
    const float4* lfr4_1 = (const float4*)(p.lfrh_w + o1);
    const float4* rfl4_0 = (const float4*)(p.rflh_w + o0);
    const float4* rfl4_1 = (const float4*)(p.rflh_w + o1);
    const float4* rfr4_0 = (const float4*)(p.rfrh_w + o0);
    const float4* rfr4_1 = (const float4*)(p.rfrh_w + o1);
    const float4* ul4_0  = (const float4*)(p.ulh_w  + o0);
    const float4* ul4_1  = (const float4*)(p.ulh_w  + o1);
    const float4* ur4_0  = (const float4*)(p.urh_w  + o0);
    const float4* ur4_1  = (const float4*)(p.urh_w  + o1);

    float gi0 = 0.f, glf0 = 0.f, grf0 = 0.f, gu0 = 0.f;
    float gi1 = 0.f, glf1 = 0.f, grf1 = 0.f, gu1 = 0.f;
#pragma unroll
    for (int h = 0; h < 2; ++h) {
        const int i = t + h * NT;
        const float4 wA = il4_0[i];
        const float4 wB = ir4_0[i];
        const float4 wC = lfl4_0[i];
        const float4 wD = lfr4_0[i];
        const float4 wE = rfl4_0[i];
        const float4 wF = rfr4_0[i];
        const float4 wG = ul4_0[i];
        const float4 wH = ur4_0[i];
        const float4 wI = il4_1[i];
        const float4 wJ = ir4_1[i];
        const float4 wK = lfl4_1[i];
        const float4 wL = lfr4_1[i];
        const float4 wM = rfl4_1[i];
        const float4 wN = rfr4_1[i];
        const float4 wO = ul4_1[i];
        const float4 wP = ur4_1[i];
        gi0  += dot4(wA, xa[h]) + dot4(wB, xb[h]);
        glf0 += dot4(wC, xa[h]) + dot4(wD, xb[h]);
        grf0 += dot4(wE, xa[h]) + dot4(wF, xb[h]);
        gu0  += dot4(wG, xa[h]) + dot4(wH, xb[h]);
        gi1  += dot4(wI, xa[h]) + dot4(wJ, xb[h]);
        glf1 += dot4(wK, xa[h]) + dot4(wL, xb[h]);
        grf1 += dot4(wM, xa[h]) + dot4(wN, xb[h]);
        gu1  += dot4(wO, xa[h]) + dot4(wP, xb[h]);
    }
    gi0  = wave_reduce(gi0);   gi1  = wave_reduce(gi1);
    glf0 = wave_reduce(glf0);  glf1 = wave_reduce(glf1);
    grf0 = wave_reduce(grf0);  grf1 = wave_reduce(grf1);
    gu0  = wave_reduce(gu0);   gu1  = wave_reduce(gu1);

    if (ln == 0) {
        s_red[wv][0] = gi0;  s_red[wv][1] = glf0;
        s_red[wv][2] = grf0; s_red[wv][3] = gu0;
        s_red[wv][4] = gi1;  s_red[wv][5] = glf1;
        s_red[wv][6] = grf1; s_red[wv][7] = gu1;
    }
    __syncthreads();
    if (t == 0) {
        const float bIv[2]  = { bI0, bI1 };
        const float bLFv[2] = { bLF0, bLF1 };
        const float bRFv[2] = { bRF0, bRF1 };
        const float bUv[2]  = { bU0, bU1 };
        const float lcv[2]  = { lc0, lc1 };
        const float rcv[2]  = { rc0, rc1 };
#pragma unroll
        for (int rr = 0; rr < 2; ++rr) {
            float g0 = 0.f, g1 = 0.f, g2 = 0.f, g3 = 0.f;
#pragma unroll
            for (int k = 0; k < 4; ++k) {
                g0 += s_red[k][rr * 4 + 0];
                g1 += s_red[k][rr * 4 + 1];
                g2 += s_red[k][rr * 4 + 2];
                g3 += s_red[k][rr * 4 + 3];
            }
            const float ig  = sigmoid_fast(g0 + bIv[rr]);
            const float lfg = sigmoid_fast(g1 + bLFv[rr]);
            const float rfg = sigmoid_fast(g2 + bRFv[rr]);
            const float ug  = tanh_fast(g3 + bUv[rr]);
            const float c   = ig * ug + lfg * lcv[rr] + rfg * rcv[rr];
            const int row = r0 + rr;
            p.out[row]       = c;
            p.out[MEM + row] = tanh_fast(c);
        }
    }
}

extern "C" void kernel_launch(void* const* d_in, const int* in_sizes, int n_in,
                              void* d_out, int out_size, void* d_ws, size_t ws_size,
                              hipStream_t stream)
{
    Params h;
    h.lc = (const float*)d_in[0];
    h.lh = (const float*)d_in[1];
    h.rc = (const float*)d_in[2];
    h.rh = (const float*)d_in[3];
    h.S  = (const float*)d_in[4];
    h.w  = (const float*)d_in[5];
    h.Wh_w   = (const float*)d_in[6];   h.Wh_b   = (const float*)d_in[7];
    h.Us_w   = (const float*)d_in[8];   h.Us_b   = (const float*)d_in[9];
    h.ma_w   = (const float*)d_in[10];  h.ma_b   = (const float*)d_in[11];
    h.ilh_w  = (const float*)d_in[12];  h.ilh_b  = (const float*)d_in[13];
    h.irh_w  = (const float*)d_in[14];  h.irh_b  = (const float*)d_in[15];
    h.lflh_w = (const float*)d_in[16];  h.lflh_b = (const float*)d_in[17];
    h.lfrh_w = (const float*)d_in[18];  h.lfrh_b = (const float*)d_in[19];
    h.rflh_w = (const float*)d_in[20];  h.rflh_b = (const float*)d_in[21];
    h.rfrh_w = (const float*)d_in[22];  h.rfrh_b = (const float*)d_in[23];
    h.ulh_w  = (const float*)d_in[24];  h.ulh_b  = (const float*)d_in[25];
    h.urh_w  = (const float*)d_in[26];  h.urh_b  = (const float*)d_in[27];

    float* ws = (float*)d_ws;
    h.pl  = ws;
    h.pr  = ws + MEM;
    h.wml = ws + 2 * MEM;
    h.wmr = ws + 3 * MEM;
    h.out = (float*)d_out;

    k1<<<NBLK, NT, 0, stream>>>(h);
    k2<<<NBLK, NT, 0, stream>>>(h);
}

// Round 3
// 241.318 us; speedup vs baseline: 1.0273x; 1.0273x over previous
//
#include <hip/hip_runtime.h>
#include <math.h>

#define MEM  2048
#define NT   256

struct Params {
    const float *lc, *rc, *lh, *rh, *S, *w;
    const float *Wh_w, *Wh_b, *Us_w, *Us_b, *ma_w, *ma_b;
    const float *ilh_w, *ilh_b, *irh_w, *irh_b;
    const float *lflh_w, *lflh_b, *lfrh_w, *lfrh_b;
    const float *rflh_w, *rflh_b, *rfrh_w, *rfrh_b;
    const float *ulh_w, *ulh_b, *urh_w, *urh_b;
    float *pl, *pr, *wml, *wmr, *out;
};

__device__ __forceinline__ float dot4(float4 a, float4 b) {
    return a.x * b.x + a.y * b.y + a.z * b.z + a.w * b.w;
}

__device__ __forceinline__ float wave_reduce(float v) {
#pragma unroll
    for (int off = 32; off > 0; off >>= 1)
        v += __shfl_down(v, off, 64);
    return v;
}

// fast tanh/sigmoid via v_exp; |err| ~1e-6 vs libm, tolerance is 3.9e-3.
__device__ __forceinline__ float tanh_fast(float x) {
    x = fminf(15.0f, fmaxf(-15.0f, x));
    const float e = __expf(2.0f * x);
    return (e - 1.0f) / (e + 1.0f);
}
__device__ __forceinline__ float sigmoid_fast(float x) {
    return 1.0f / (1.0f + __expf(-x));
}

// ---- k1: one block per row (grid=2048) — round-0 structure (best measured).
//   pl[j] = ma_w[j]·lh ; pr[j] = ma_w[j]·rh        (alpha hoisted)
//   m_l = tanh(Wh_w[j]·lh + Wh_b[j] + Us_w[j]·S + Us_b[j]) ; m_r likewise
//   wml[j] = w[j]*m_l ; wmr[j] = w[j]*m_r
__global__ __launch_bounds__(NT) void k1(Params p)
{
    __shared__ float s_red[4][5];

    const int t   = threadIdx.x;
    const int row = blockIdx.x;

    const float4* wh4 = (const float4*)(p.Wh_w + (size_t)row * MEM);
    const float4* us4 = (const float4*)(p.Us_w + (size_t)row * MEM);
    const float4* ma4 = (const float4*)(p.ma_w + (size_t)row * MEM);
    const float4* l4  = (const float4*)p.lh;
    const float4* r4  = (const float4*)p.rh;
    const float4* s4  = (const float4*)p.S;

    float awl = 0.f, awr = 0.f, aus = 0.f, aml = 0.f, amr = 0.f;
#pragma unroll
    for (int h = 0; h < 2; ++h) {
        const int i = t + h * NT;
        const float4 a  = wh4[i];
        const float4 u  = us4[i];
        const float4 m  = ma4[i];
        const float4 xl = l4[i];
        const float4 xr = r4[i];
        const float4 xs = s4[i];
        awl += dot4(a, xl);
        awr += dot4(a, xr);
        aus += dot4(u, xs);
        aml += dot4(m, xl);
        amr += dot4(m, xr);
    }
    awl = wave_reduce(awl);
    awr = wave_reduce(awr);
    aus = wave_reduce(aus);
    aml = wave_reduce(aml);
    amr = wave_reduce(amr);

    const int wv = t >> 6, ln = t & 63;
    if (ln == 0) {
        s_red[wv][0] = awl; s_red[wv][1] = awr; s_red[wv][2] = aus;
        s_red[wv][3] = aml; s_red[wv][4] = amr;
    }
    __syncthreads();
    if (t == 0) {
        float r0 = 0.f, r1 = 0.f, r2 = 0.f, r3 = 0.f, r4v = 0.f;
#pragma unroll
        for (int k = 0; k < 4; ++k) {
            r0 += s_red[k][0]; r1 += s_red[k][1]; r2 += s_red[k][2];
            r3 += s_red[k][3]; r4v += s_red[k][4];
        }
        const float us = r2 + p.Us_b[row];
        const float ml = tanh_fast(r0 + p.Wh_b[row] + us);
        const float mr = tanh_fast(r1 + p.Wh_b[row] + us);
        p.pl[row] = r3;
        p.pr[row] = r4v;
        const float wj = p.w[row];
        p.wml[row] = wj * ml;
        p.wmr[row] = wj * mr;
    }
}

// ---- k2: one block per row (grid=2048), copy-bench-shaped streaming:
//  phase 1: block-redundant alpha reduce (16 KB, L2-broadcast)
//  phase 2: xa/xb = tanh(alpha*p + ma_b) into LDS
//  phase 3: WAVE-OWNED streams — wave wv computes gate[wv] = Wl·xa + Wr·xb
//           over the full row: 2 streams x 8 contiguous float4 loads/lane,
//           zero syncs inside the loop, one wave_reduce at the end.
__global__ __launch_bounds__(NT, 8) void k2(Params p)
{
    __shared__ __align__(16) float s_xa[MEM];
    __shared__ __align__(16) float s_xb[MEM];
    __shared__ float s_red[4][2];
    __shared__ float s_g[4];
    __shared__ float s_al[2];

    const int t   = threadIdx.x;
    const int wv  = t >> 6, ln = t & 63;
    const int row = blockIdx.x;

    // per-row scalars (wave-uniform -> scalar loads), prefetched at the top
    const float bI  = p.ilh_b[row]  + p.irh_b[row];
    const float bLF = p.lflh_b[row] + p.lfrh_b[row];
    const float bRF = p.rflh_b[row] + p.rfrh_b[row];
    const float bU  = p.ulh_b[row]  + p.urh_b[row];
    const float lcv = p.lc[row], rcv = p.rc[row];

    // ---- phase 1: alpha ----
    {
        const float4* wl4 = (const float4*)p.wml;
        const float4* wr4 = (const float4*)p.wmr;
        const float4 a0 = wl4[t], a1 = wl4[t + NT];
        const float4 b0 = wr4[t], b1 = wr4[t + NT];
        float el = a0.x + a0.y + a0.z + a0.w + a1.x + a1.y + a1.z + a1.w;
        float er = b0.x + b0.y + b0.z + b0.w + b1.x + b1.y + b1.z + b1.w;
        el = wave_reduce(el);
        er = wave_reduce(er);
        if (ln == 0) { s_red[wv][0] = el; s_red[wv][1] = er; }
    }
    __syncthreads();
    if (t == 0) {
        const float el = s_red[0][0] + s_red[1][0] + s_red[2][0] + s_red[3][0];
        const float er = s_red[0][1] + s_red[1][1] + s_red[2][1] + s_red[3][1];
        const float d  = el + er;
        s_al[0] = el / d;
        s_al[1] = er / d;
    }
    __syncthreads();
    const float al = s_al[0];
    const float ar = s_al[1];

    // ---- phase 2: xa/xb into LDS ----
    {
        const float4* p4 = (const float4*)p.pl;
        const float4* q4 = (const float4*)p.pr;
        const float4* b4 = (const float4*)p.ma_b;
        float4* sxa4 = (float4*)s_xa;
        float4* sxb4 = (float4*)s_xb;
#pragma unroll
        for (int h = 0; h < 2; ++h) {
            const int i = t + h * NT;
            const float4 pp = p4[i];
            const float4 qq = q4[i];
            const float4 bb = b4[i];
            float4 xa, xb;
            xa.x = tanh_fast(al * pp.x + bb.x); xb.x = tanh_fast(ar * qq.x + bb.x);
            xa.y = tanh_fast(al * pp.y + bb.y); xb.y = tanh_fast(ar * qq.y + bb.y);
            xa.z = tanh_fast(al * pp.z + bb.z); xb.z = tanh_fast(ar * qq.z + bb.z);
            xa.w = tanh_fast(al * pp.w + bb.w); xb.w = tanh_fast(ar * qq.w + bb.w);
            sxa4[i] = xa;
            sxb4[i] = xb;
        }
    }
    __syncthreads();

    // ---- phase 3: wave-owned streams ----
    // wv0: (ilh, irh) -> i ; wv1: (lflh, lfrh) -> lf ;
    // wv2: (rflh, rfrh) -> rf ; wv3: (ulh, urh) -> u
    const float *wlp, *wrp;
    if      (wv == 0) { wlp = p.ilh_w;  wrp = p.irh_w;  }
    else if (wv == 1) { wlp = p.lflh_w; wrp = p.lfrh_w; }
    else if (wv == 2) { wlp = p.rflh_w; wrp = p.rfrh_w; }
    else              { wlp = p.ulh_w;  wrp = p.urh_w;  }

    const float4* wl4 = (const float4*)(wlp + (size_t)row * MEM);
    const float4* wr4 = (const float4*)(wrp + (size_t)row * MEM);
    const float4* xa4 = (const float4*)s_xa;
    const float4* xb4 = (const float4*)s_xb;

    float accA = 0.f, accB = 0.f;
#pragma unroll
    for (int j = 0; j < 8; ++j) {
        const int i = ln + 64 * j;
        accA += dot4(wl4[i], xa4[i]);
        accB += dot4(wr4[i], xb4[i]);
    }
    const float g = wave_reduce(accA + accB);
    if (ln == 0) s_g[wv] = g;
    __syncthreads();

    if (t == 0) {
        const float ig  = sigmoid_fast(s_g[0] + bI);
        const float lfg = sigmoid_fast(s_g[1] + bLF);
        const float rfg = sigmoid_fast(s_g[2] + bRF);
        const float ug  = tanh_fast(s_g[3] + bU);
        const float c   = ig * ug + lfg * lcv + rfg * rcv;
        p.out[row]       = c;
        p.out[MEM + row] = tanh_fast(c);
    }
}

extern "C" void kernel_launch(void* const* d_in, const int* in_sizes, int n_in,
                              void* d_out, int out_size, void* d_ws, size_t ws_size,
                              hipStream_t stream)
{
    Params h;
    h.lc = (const float*)d_in[0];
    h.lh = (const float*)d_in[1];
    h.rc = (const float*)d_in[2];
    h.rh = (const float*)d_in[3];
    h.S  = (const float*)d_in[4];
    h.w  = (const float*)d_in[5];
    h.Wh_w   = (const float*)d_in[6];   h.Wh_b   = (const float*)d_in[7];
    h.Us_w   = (const float*)d_in[8];   h.Us_b   = (const float*)d_in[9];
    h.ma_w   = (const float*)d_in[10];  h.ma_b   = (const float*)d_in[11];
    h.ilh_w  = (const float*)d_in[12];  h.ilh_b  = (const float*)d_in[13];
    h.irh_w  = (const float*)d_in[14];  h.irh_b  = (const float*)d_in[15];
    h.lflh_w = (const float*)d_in[16];  h.lflh_b = (const float*)d_in[17];
    h.lfrh_w = (const float*)d_in[18];  h.lfrh_b = (const float*)d_in[19];
    h.rflh_w = (const float*)d_in[20];  h.rflh_b = (const float*)d_in[21];
    h.rfrh_w = (const float*)d_in[22];  h.rfrh_b = (const float*)d_in[23];
    h.ulh_w  = (const float*)d_in[24];  h.ulh_b  = (const float*)d_in[25];
    h.urh_w  = (const float*)d_in[26];  h.urh_b  = (const float*)d_in[27];

    float* ws = (float*)d_ws;
    h.pl  = ws;
    h.pr  = ws + MEM;
    h.wml = ws + 2 * MEM;
    h.wmr = ws + 3 * MEM;
    h.out = (float*)d_out;

    k1<<<MEM, NT, 0, stream>>>(h);
    k2<<<MEM, NT, 0, stream>>>(h);
}